// Round 4
// baseline (249.902 us; speedup 1.0000x reference)
//
#include <hip/hip_runtime.h>

#define NSAMP 4096
#define NITER 200

typedef float v2f __attribute__((ext_vector_type(2)));

// ---------------------------------------------------------------------------
// Setup: inv_item = inv(A^T A + 2*DtD + 5*I) via Woodbury (unchanged from R3:
// circulant Binv via Chebyshev DFT sum, rank-9 correction via parallel GJ).
// ---------------------------------------------------------------------------
__global__ __launch_bounds__(256) void setup_woodbury(const float* __restrict__ A,
                                                      float* __restrict__ inv_out) {
  __shared__ double lamr[64];
  __shared__ float binv[64];
  __shared__ float P[9][64];
  __shared__ float Q[9][64];
  __shared__ double W[9][18];
  const int tid = threadIdx.x;
  const double TWO_PI = 6.283185307179586476925286766559;

  double cb = 0.0;
  if (tid < 64) {
    cb = cos(TWO_PI * (double)tid / 64.0);
    lamr[tid] = 1.0 / (9.0 - 4.0 * cb);
  }
  __syncthreads();
  if (tid < 64) {
    double cm1 = 1.0, c0 = cb;
    double acc = lamr[0] + cb * lamr[1];
#pragma unroll 16
    for (int m = 2; m < 64; ++m) {
      double c = 2.0 * cb * c0 - cm1;
      cm1 = c0;
      c0 = c;
      acc += c * lamr[m];
    }
    binv[tid] = (float)(acc / 64.0);
  }
  __syncthreads();

  for (int e = tid; e < 9 * 64; e += 256) {
    int m = e >> 6, i = e & 63;
    double acc = 0.0;
#pragma unroll 16
    for (int k = 0; k < 64; ++k)
      acc += (double)A[m * 64 + k] * (double)binv[(k - i) & 63];
    P[m][i] = (float)acc;
  }
  __syncthreads();

  if (tid < 81) {
    int m = tid / 9, n = tid % 9;
    double acc = (m == n) ? 1.0 : 0.0;
#pragma unroll 16
    for (int i = 0; i < 64; ++i)
      acc += (double)P[m][i] * (double)A[n * 64 + i];
    W[m][n] = acc;
    W[m][n + 9] = (m == n) ? 1.0 : 0.0;
  }
  __syncthreads();

  {
    const int r9 = tid / 18, c9 = tid % 18;
    const bool act = (tid < 162);
    for (int k = 0; k < 9; ++k) {
      double pv = 1.0, f = 0.0, wkc = 0.0;
      if (act) {
        pv = W[k][k];
        f = W[r9][k];
        wkc = W[k][c9];
      }
      __syncthreads();
      if (act) {
        double nk = wkc / pv;
        W[r9][c9] = (r9 == k) ? nk : fma(-f, nk, W[r9][c9]);
      }
      __syncthreads();
    }
  }

  for (int e = tid; e < 9 * 64; e += 256) {
    int m = e >> 6, j = e & 63;
    double acc = 0.0;
#pragma unroll
    for (int n = 0; n < 9; ++n) acc += W[m][n + 9] * (double)P[n][j];
    Q[m][j] = (float)acc;
  }
  __syncthreads();

  for (int e = tid; e < 64 * 64; e += 256) {
    int i = e >> 6, j = e & 63;
    float acc = binv[(i - j) & 63];
#pragma unroll
    for (int m = 0; m < 9; ++m) acc = fmaf(-P[m][i], Q[m][j], acc);
    inv_out[e] = acc;
  }
}

// ---------------------------------------------------------------------------
// Main ADMM kernel, R4 structure: TWO waves per sample.
//   wave pair member `half` holds M[lane][half*32 .. half*32+31] (32 VGPRs —
//   inside the ~50-reg working set the allocator handles without AGPR parking
//   or remat-sinking, per R1-R3 evidence).
// Per iter: both waves compute the pointwise math identically (bitwise
// lockstep), each does its half mat-vec from its private LDS resid copy
// (8 ds_read_b128 + 16 v_pk_fma_f32), partials exchanged via parity-double-
// buffered LDS with ONE __syncthreads per iteration.
// Grid: 2048 blocks x 4 waves = 32 waves/CU (100% occupancy at <=64 VGPR).
// ---------------------------------------------------------------------------
__global__ __launch_bounds__(256)
void admm_kernel(const float* __restrict__ target, const float* __restrict__ A,
                 const float* __restrict__ x0, const float* __restrict__ invmat,
                 float* __restrict__ out) {
  __shared__ __align__(16) float rbuf[4][64];   // per-wave resid copy
  __shared__ float pbuf[2][4][64];              // [parity][wave][lane]
  const int tid = threadIdx.x;
  const int wid = tid >> 6;
  const int lane = tid & 63;
  const int pairI = wid >> 1;    // sample within block
  const int half = wid & 1;      // 0: cols 0-31, 1: cols 32-63
  const int s = blockIdx.x * 2 + pairI;

  // --- ATb (one-time, duplicated in both waves of the pair) ---
  float t = target[s * 64 + lane];
  float atb = 0.f;
#pragma unroll
  for (int m = 0; m < 9; ++m) {
    float a = A[m * 64 + lane];
    float p = t * a;
#pragma unroll
    for (int off = 32; off; off >>= 1) p += __shfl_xor(p, off, 64);
    atb = fmaf(a, p, atb);
  }

  // --- M half-row: 16 float2 pairs (32 VGPRs) ---
  const float* mrow = invmat + lane * 64 + half * 32;
  v2f m0, m1, m2, m3, m4, m5, m6, m7, m8, m9, m10, m11, m12, m13, m14, m15;
#define LOADQ(q, ma, mb)                                              \
  {                                                                   \
    float4 v = reinterpret_cast<const float4*>(mrow)[q];              \
    ma = (v2f){v.x, v.y};                                             \
    mb = (v2f){v.z, v.w};                                             \
  }
  LOADQ(0, m0, m1) LOADQ(1, m2, m3) LOADQ(2, m4, m5) LOADQ(3, m6, m7)
  LOADQ(4, m8, m9) LOADQ(5, m10, m11) LOADQ(6, m12, m13) LOADQ(7, m14, m15)
#undef LOADQ

  float* rb = &rbuf[wid][0];
  const float* rhalf = &rbuf[wid][half * 32];
  float x = x0[s * 64 + lane];
  float eta = 0.f, tau = 0.f;
  const int nxt = (lane + 1) & 63;
  float Dx = __shfl(x, nxt, 64) - x;

#pragma unroll 1
  for (int it = 0; it < NITER; ++it) {
    // u = soft_thresh(Dx + eta/2, 5e-5); w = relu(x + tau/5)
    float v = fmaf(eta, 0.5f, Dx);
    float u = copysignf(fmaxf(fabsf(v) - 5e-5f, 0.f), v);
    float w = fmaxf(fmaf(tau, 0.2f, x), 0.f);
    float tv = fmaf(2.f, u, -eta);
    float ts = __shfl(tv, nxt, 64);
    float resid = fmaf(5.f, w, atb) + (ts - tv) - tau;

    rb[lane] = resid;
    __builtin_amdgcn_wave_barrier();

    // half mat-vec: 8 broadcast b128 reads + 16 packed-fp32 FMAs, 2 chains
    v2f a0 = {0.f, 0.f}, a1 = {0.f, 0.f};
#define STEP2(j, mA, mB)                                                    \
    {                                                                       \
      float4 r4 = *reinterpret_cast<const float4*>(rhalf + 4 * (j));        \
      v2f rlo = {r4.x, r4.y};                                               \
      v2f rhi = {r4.z, r4.w};                                               \
      asm("v_pk_fma_f32 %0, %1, %2, %0" : "+v"(a0) : "v"(mA), "v"(rlo));    \
      asm("v_pk_fma_f32 %0, %1, %2, %0" : "+v"(a1) : "v"(mB), "v"(rhi));    \
    }
    STEP2(0, m0, m1)  STEP2(1, m2, m3)  STEP2(2, m4, m5)  STEP2(3, m6, m7)
    STEP2(4, m8, m9)  STEP2(5, m10, m11) STEP2(6, m12, m13) STEP2(7, m14, m15)
#undef STEP2
    float p = (a0.x + a0.y) + (a1.x + a1.y);

    // exchange partials with pair wave (parity double-buffer, one barrier)
    const int par = it & 1;
    pbuf[par][wid][lane] = p;
    __syncthreads();
    float po = pbuf[par][wid ^ 1][lane];
    float xn = p + po;   // commutative: bitwise identical in both waves

    float xs2 = __shfl(xn, nxt, 64);
    Dx = xs2 - xn;
    eta = fmaf(2.f, Dx - u, eta);
    tau = fmaf(5.f, xn - w, tau);
    x = xn;
  }

  if (half == 0) out[s * 64 + lane] = x;
}

extern "C" void kernel_launch(void* const* d_in, const int* in_sizes, int n_in,
                              void* d_out, int out_size, void* d_ws, size_t ws_size,
                              hipStream_t stream) {
  const float* target = (const float*)d_in[0];  // (4096, 64)
  const float* A = (const float*)d_in[1];       // (9, 64)
  const float* x0 = (const float*)d_in[2];      // (4096, 64)
  float* out = (float*)d_out;                   // (4096, 64)
  float* inv_ws = (float*)d_ws;                 // 64*64 floats scratch

  setup_woodbury<<<1, 256, 0, stream>>>(A, inv_ws);
  admm_kernel<<<NSAMP / 2, 256, 0, stream>>>(target, A, x0, inv_ws, out);
}

// Round 5
// 202.628 us; speedup vs baseline: 1.2333x; 1.2333x over previous
//
#include <hip/hip_runtime.h>

#define NSAMP 4096
#define NITER 200

// ---------------------------------------------------------------------------
// Setup: inv_item = inv(A^T A + 2*DtD + 5*I) via Woodbury (unchanged from R3:
// circulant Binv via Chebyshev DFT sum, rank-9 correction via parallel GJ).
// ---------------------------------------------------------------------------
__global__ __launch_bounds__(256) void setup_woodbury(const float* __restrict__ A,
                                                      float* __restrict__ inv_out) {
  __shared__ double lamr[64];
  __shared__ float binv[64];
  __shared__ float P[9][64];
  __shared__ float Q[9][64];
  __shared__ double W[9][18];
  const int tid = threadIdx.x;
  const double TWO_PI = 6.283185307179586476925286766559;

  double cb = 0.0;
  if (tid < 64) {
    cb = cos(TWO_PI * (double)tid / 64.0);
    lamr[tid] = 1.0 / (9.0 - 4.0 * cb);
  }
  __syncthreads();
  if (tid < 64) {
    double cm1 = 1.0, c0 = cb;
    double acc = lamr[0] + cb * lamr[1];
#pragma unroll 16
    for (int m = 2; m < 64; ++m) {
      double c = 2.0 * cb * c0 - cm1;
      cm1 = c0;
      c0 = c;
      acc += c * lamr[m];
    }
    binv[tid] = (float)(acc / 64.0);
  }
  __syncthreads();

  for (int e = tid; e < 9 * 64; e += 256) {
    int m = e >> 6, i = e & 63;
    double acc = 0.0;
#pragma unroll 16
    for (int k = 0; k < 64; ++k)
      acc += (double)A[m * 64 + k] * (double)binv[(k - i) & 63];
    P[m][i] = (float)acc;
  }
  __syncthreads();

  if (tid < 81) {
    int m = tid / 9, n = tid % 9;
    double acc = (m == n) ? 1.0 : 0.0;
#pragma unroll 16
    for (int i = 0; i < 64; ++i)
      acc += (double)P[m][i] * (double)A[n * 64 + i];
    W[m][n] = acc;
    W[m][n + 9] = (m == n) ? 1.0 : 0.0;
  }
  __syncthreads();

  {
    const int r9 = tid / 18, c9 = tid % 18;
    const bool act = (tid < 162);
    for (int k = 0; k < 9; ++k) {
      double pv = 1.0, f = 0.0, wkc = 0.0;
      if (act) {
        pv = W[k][k];
        f = W[r9][k];
        wkc = W[k][c9];
      }
      __syncthreads();
      if (act) {
        double nk = wkc / pv;
        W[r9][c9] = (r9 == k) ? nk : fma(-f, nk, W[r9][c9]);
      }
      __syncthreads();
    }
  }

  for (int e = tid; e < 9 * 64; e += 256) {
    int m = e >> 6, j = e & 63;
    double acc = 0.0;
#pragma unroll
    for (int n = 0; n < 9; ++n) acc += W[m][n + 9] * (double)P[n][j];
    Q[m][j] = (float)acc;
  }
  __syncthreads();

  for (int e = tid; e < 64 * 64; e += 256) {
    int i = e >> 6, j = e & 63;
    float acc = binv[(i - j) & 63];
#pragma unroll
    for (int m = 0; m < 9; ++m) acc = fmaf(-P[m][i], Q[m][j], acc);
    inv_out[e] = acc;
  }
}

// ---------------------------------------------------------------------------
// Main ADMM kernel, R5: entire 200-iteration loop is ONE asm volatile block
// with hard physical registers (allocator removed from the equation):
//   v64-v127 : inv_item row `lane` (16x global_load_dwordx4 in prologue)
//   v32-v47  : state (x,eta,tau,Dx,atb,temps) + 2 packed acc pairs
//   v48-v63  : 4 quads, 4-deep software-pipelined ds_read_b128 of resid
// Per iter: 8 ptwise VALU -> bpermute(tv) -> resid -> ds_write -> 16 b128
// reads w/ counted lgkmcnt(3) -> 32 v_pk_fma_f32 -> bpermute(xn) -> duals.
// No barriers (all LDS strictly wave-private; same-wave DS retires in order).
// Clobbers v32-v127 => VGPR_Count=128 => 4 waves/SIMD, grid fully resident.
// ---------------------------------------------------------------------------
__global__ __launch_bounds__(256)
void admm_kernel(const float* __restrict__ target, const float* __restrict__ A,
                 const float* __restrict__ x0, const float* __restrict__ invmat,
                 float* __restrict__ out) {
  __shared__ __align__(16) float rbuf[4][64];
  const int tid = threadIdx.x;
  const int wid = tid >> 6;
  const int lane = tid & 63;
  const int s = blockIdx.x * 4 + wid;

  // --- ATb = (target_s @ A^T) @ A via 9 wave-reductions (one-time) ---
  float t = target[s * 64 + lane];
  float atbv = 0.f;
#pragma unroll
  for (int m = 0; m < 9; ++m) {
    float a = A[m * 64 + lane];
    float p = t * a;
#pragma unroll
    for (int off = 32; off; off >>= 1) p += __shfl_xor(p, off, 64);
    atbv = fmaf(a, p, atbv);
  }

  const float* mrow = invmat + (size_t)lane * 64;
  // generic->LDS: low 32 bits of the generic address are the LDS byte offset
  unsigned int rb_base = (unsigned int)(uintptr_t)(&rbuf[wid][0]);
  unsigned int a_w = rb_base + lane * 4;
  unsigned int a_nxt = ((lane + 1) & 63) * 4;  // ds_bpermute byte index
  float xin = x0[s * 64 + lane];
  float xout;
  int cnt_s;
  const int smask = 0x7fffffff;
  const float sthr = 5e-5f, sc02 = 0.2f, sc5 = 5.0f;

  asm volatile(
      "s_mov_b32 m0, -1\n\t"
      // --- load inv row into v64-v127 ---
      "global_load_dwordx4 v[64:67],   %[mp], off\n\t"
      "global_load_dwordx4 v[68:71],   %[mp], off offset:16\n\t"
      "global_load_dwordx4 v[72:75],   %[mp], off offset:32\n\t"
      "global_load_dwordx4 v[76:79],   %[mp], off offset:48\n\t"
      "global_load_dwordx4 v[80:83],   %[mp], off offset:64\n\t"
      "global_load_dwordx4 v[84:87],   %[mp], off offset:80\n\t"
      "global_load_dwordx4 v[88:91],   %[mp], off offset:96\n\t"
      "global_load_dwordx4 v[92:95],   %[mp], off offset:112\n\t"
      "global_load_dwordx4 v[96:99],   %[mp], off offset:128\n\t"
      "global_load_dwordx4 v[100:103], %[mp], off offset:144\n\t"
      "global_load_dwordx4 v[104:107], %[mp], off offset:160\n\t"
      "global_load_dwordx4 v[108:111], %[mp], off offset:176\n\t"
      "global_load_dwordx4 v[112:115], %[mp], off offset:192\n\t"
      "global_load_dwordx4 v[116:119], %[mp], off offset:208\n\t"
      "global_load_dwordx4 v[120:123], %[mp], off offset:224\n\t"
      "global_load_dwordx4 v[124:127], %[mp], off offset:240\n\t"
      // --- init state: v32=x v33=eta v34=tau v35=Dx v36=atb ---
      "v_mov_b32 v32, %[xin]\n\t"
      "v_mov_b32 v36, %[atb]\n\t"
      "v_mov_b32 v33, 0\n\t"
      "v_mov_b32 v34, 0\n\t"
      "ds_bpermute_b32 v45, %[anx], v32\n\t"
      "s_waitcnt lgkmcnt(0)\n\t"
      "v_sub_f32 v35, v45, v32\n\t"
      "s_movk_i32 %[cnt], 200\n\t"
      "s_waitcnt vmcnt(0)\n\t"
      "1:\n\t"
      // u = copysign(max(|0.5*eta+Dx|-thr,0), 0.5*eta+Dx)   -> v42
      "v_fma_f32 v40, 0.5, v33, v35\n\t"
      "v_and_b32 v41, %[msk], v40\n\t"
      "v_subrev_f32 v41, %[thr], v41\n\t"
      "v_max_f32 v41, 0, v41\n\t"
      "v_bfi_b32 v42, %[msk], v41, v40\n\t"
      // w = max(0.2*tau + x, 0)                             -> v43
      "v_fma_f32 v43, %[c02], v34, v32\n\t"
      "v_max_f32 v43, 0, v43\n\t"
      // tv = 2u - eta -> v40 ; ts = tv[lane+1] -> v45
      "v_fma_f32 v40, 2.0, v42, -v33\n\t"
      "ds_bpermute_b32 v45, %[anx], v40\n\t"
      // resid = 5w + atb - tau - tv + ts                    -> v44
      "v_fma_f32 v44, %[c5], v43, v36\n\t"
      "v_sub_f32 v44, v44, v34\n\t"
      "v_sub_f32 v44, v44, v40\n\t"
      "s_waitcnt lgkmcnt(0)\n\t"
      "v_add_f32 v44, v44, v45\n\t"
      "ds_write_b32 %[aw], v44\n\t"
      // matvec: 16 chunks, 4-deep pipelined b128 reads, counted lgkmcnt
      "ds_read_b128 v[48:51], %[rb]\n\t"
      "ds_read_b128 v[52:55], %[rb] offset:16\n\t"
      "ds_read_b128 v[56:59], %[rb] offset:32\n\t"
      "ds_read_b128 v[60:63], %[rb] offset:48\n\t"
      "s_waitcnt lgkmcnt(3)\n\t"                                  // j=0
      "v_pk_mul_f32 v[44:45], v[64:65], v[48:49]\n\t"
      "v_pk_mul_f32 v[46:47], v[66:67], v[50:51]\n\t"
      "ds_read_b128 v[48:51], %[rb] offset:64\n\t"
      "s_waitcnt lgkmcnt(3)\n\t"                                  // j=1
      "v_pk_fma_f32 v[44:45], v[68:69], v[52:53], v[44:45]\n\t"
      "v_pk_fma_f32 v[46:47], v[70:71], v[54:55], v[46:47]\n\t"
      "ds_read_b128 v[52:55], %[rb] offset:80\n\t"
      "s_waitcnt lgkmcnt(3)\n\t"                                  // j=2
      "v_pk_fma_f32 v[44:45], v[72:73], v[56:57], v[44:45]\n\t"
      "v_pk_fma_f32 v[46:47], v[74:75], v[58:59], v[46:47]\n\t"
      "ds_read_b128 v[56:59], %[rb] offset:96\n\t"
      "s_waitcnt lgkmcnt(3)\n\t"                                  // j=3
      "v_pk_fma_f32 v[44:45], v[76:77], v[60:61], v[44:45]\n\t"
      "v_pk_fma_f32 v[46:47], v[78:79], v[62:63], v[46:47]\n\t"
      "ds_read_b128 v[60:63], %[rb] offset:112\n\t"
      "s_waitcnt lgkmcnt(3)\n\t"                                  // j=4
      "v_pk_fma_f32 v[44:45], v[80:81], v[48:49], v[44:45]\n\t"
      "v_pk_fma_f32 v[46:47], v[82:83], v[50:51], v[46:47]\n\t"
      "ds_read_b128 v[48:51], %[rb] offset:128\n\t"
      "s_waitcnt lgkmcnt(3)\n\t"                                  // j=5
      "v_pk_fma_f32 v[44:45], v[84:85], v[52:53], v[44:45]\n\t"
      "v_pk_fma_f32 v[46:47], v[86:87], v[54:55], v[46:47]\n\t"
      "ds_read_b128 v[52:55], %[rb] offset:144\n\t"
      "s_waitcnt lgkmcnt(3)\n\t"                                  // j=6
      "v_pk_fma_f32 v[44:45], v[88:89], v[56:57], v[44:45]\n\t"
      "v_pk_fma_f32 v[46:47], v[90:91], v[58:59], v[46:47]\n\t"
      "ds_read_b128 v[56:59], %[rb] offset:160\n\t"
      "s_waitcnt lgkmcnt(3)\n\t"                                  // j=7
      "v_pk_fma_f32 v[44:45], v[92:93], v[60:61], v[44:45]\n\t"
      "v_pk_fma_f32 v[46:47], v[94:95], v[62:63], v[46:47]\n\t"
      "ds_read_b128 v[60:63], %[rb] offset:176\n\t"
      "s_waitcnt lgkmcnt(3)\n\t"                                  // j=8
      "v_pk_fma_f32 v[44:45], v[96:97], v[48:49], v[44:45]\n\t"
      "v_pk_fma_f32 v[46:47], v[98:99], v[50:51], v[46:47]\n\t"
      "ds_read_b128 v[48:51], %[rb] offset:192\n\t"
      "s_waitcnt lgkmcnt(3)\n\t"                                  // j=9
      "v_pk_fma_f32 v[44:45], v[100:101], v[52:53], v[44:45]\n\t"
      "v_pk_fma_f32 v[46:47], v[102:103], v[54:55], v[46:47]\n\t"
      "ds_read_b128 v[52:55], %[rb] offset:208\n\t"
      "s_waitcnt lgkmcnt(3)\n\t"                                  // j=10
      "v_pk_fma_f32 v[44:45], v[104:105], v[56:57], v[44:45]\n\t"
      "v_pk_fma_f32 v[46:47], v[106:107], v[58:59], v[46:47]\n\t"
      "ds_read_b128 v[56:59], %[rb] offset:224\n\t"
      "s_waitcnt lgkmcnt(3)\n\t"                                  // j=11
      "v_pk_fma_f32 v[44:45], v[108:109], v[60:61], v[44:45]\n\t"
      "v_pk_fma_f32 v[46:47], v[110:111], v[62:63], v[46:47]\n\t"
      "ds_read_b128 v[60:63], %[rb] offset:240\n\t"
      "s_waitcnt lgkmcnt(3)\n\t"                                  // j=12
      "v_pk_fma_f32 v[44:45], v[112:113], v[48:49], v[44:45]\n\t"
      "v_pk_fma_f32 v[46:47], v[114:115], v[50:51], v[46:47]\n\t"
      "s_waitcnt lgkmcnt(2)\n\t"                                  // j=13
      "v_pk_fma_f32 v[44:45], v[116:117], v[52:53], v[44:45]\n\t"
      "v_pk_fma_f32 v[46:47], v[118:119], v[54:55], v[46:47]\n\t"
      "s_waitcnt lgkmcnt(1)\n\t"                                  // j=14
      "v_pk_fma_f32 v[44:45], v[120:121], v[56:57], v[44:45]\n\t"
      "v_pk_fma_f32 v[46:47], v[122:123], v[58:59], v[46:47]\n\t"
      "s_waitcnt lgkmcnt(0)\n\t"                                  // j=15
      "v_pk_fma_f32 v[44:45], v[124:125], v[60:61], v[44:45]\n\t"
      "v_pk_fma_f32 v[46:47], v[126:127], v[62:63], v[46:47]\n\t"
      // xn = hadd -> v32 (x no longer needed)
      "v_pk_add_f32 v[44:45], v[44:45], v[46:47]\n\t"
      "v_add_f32 v32, v44, v45\n\t"
      // Dx = xn[lane+1] - xn ; duals
      "ds_bpermute_b32 v45, %[anx], v32\n\t"
      "s_waitcnt lgkmcnt(0)\n\t"
      "v_sub_f32 v35, v45, v32\n\t"
      "v_sub_f32 v41, v35, v42\n\t"
      "v_fma_f32 v33, 2.0, v41, v33\n\t"
      "v_sub_f32 v41, v32, v43\n\t"
      "v_fma_f32 v34, %[c5], v41, v34\n\t"
      "s_sub_u32 %[cnt], %[cnt], 1\n\t"
      "s_cmp_lg_u32 %[cnt], 0\n\t"
      "s_cbranch_scc1 1b\n\t"
      "v_mov_b32 %[xout], v32\n\t"
      : [xout] "=v"(xout), [cnt] "=&s"(cnt_s)
      : [mp] "v"(mrow), [rb] "v"(rb_base), [aw] "v"(a_w), [anx] "v"(a_nxt),
        [xin] "v"(xin), [atb] "v"(atbv),
        [msk] "s"(smask), [thr] "s"(sthr), [c02] "s"(sc02), [c5] "s"(sc5)
      : "memory", "scc",
        "v32","v33","v34","v35","v36","v37","v38","v39","v40","v41","v42","v43",
        "v44","v45","v46","v47","v48","v49","v50","v51","v52","v53","v54","v55",
        "v56","v57","v58","v59","v60","v61","v62","v63","v64","v65","v66","v67",
        "v68","v69","v70","v71","v72","v73","v74","v75","v76","v77","v78","v79",
        "v80","v81","v82","v83","v84","v85","v86","v87","v88","v89","v90","v91",
        "v92","v93","v94","v95","v96","v97","v98","v99","v100","v101","v102",
        "v103","v104","v105","v106","v107","v108","v109","v110","v111","v112",
        "v113","v114","v115","v116","v117","v118","v119","v120","v121","v122",
        "v123","v124","v125","v126","v127");

  out[s * 64 + lane] = xout;
}

extern "C" void kernel_launch(void* const* d_in, const int* in_sizes, int n_in,
                              void* d_out, int out_size, void* d_ws, size_t ws_size,
                              hipStream_t stream) {
  const float* target = (const float*)d_in[0];  // (4096, 64)
  const float* A = (const float*)d_in[1];       // (9, 64)
  const float* x0 = (const float*)d_in[2];      // (4096, 64)
  float* out = (float*)d_out;                   // (4096, 64)
  float* inv_ws = (float*)d_ws;                 // 64*64 floats scratch

  setup_woodbury<<<1, 256, 0, stream>>>(A, inv_ws);
  admm_kernel<<<NSAMP / 4, 256, 0, stream>>>(target, A, x0, inv_ws, out);
}